// Round 1
// baseline (255.190 us; speedup 1.0000x reference)
//
#include <hip/hip_runtime.h>
#include <float.h>

using v2f = __attribute__((ext_vector_type(2))) float;
using v4f = __attribute__((ext_vector_type(4))) float;

#define EMB 10
#define STATE 20
#define HIDDEN 40
#define NPROJ 2490

// Score one even-aligned row pair (rows 2p, 2p+1). tbl4 is indexed ONLY by the
// wave-uniform loop variable p -> uniform address -> compiler emits s_load;
// row data lives in SGPRs and feeds v_pk_fma_f32 as the one scalar operand.
__device__ __forceinline__ void score_pair(const v4f* __restrict__ tbl4, int p,
                                           const v2f wv2[5],
                                           float& best, int& bidx) {
    const v4f* tp = tbl4 + p * 5;          // pair base: byte 80*p, 16B-aligned
    v4f a0 = tp[0], a1 = tp[1], a2 = tp[2], a3 = tp[3], a4 = tp[4];
    v2f c0 = wv2[0] * a0.lo;
    c0 += wv2[1] * a0.hi; c0 += wv2[2] * a1.lo;
    c0 += wv2[3] * a1.hi; c0 += wv2[4] * a2.lo;
    float s0 = c0.x + c0.y;
    v2f c1 = wv2[0] * a2.hi;
    c1 += wv2[1] * a3.lo; c1 += wv2[2] * a3.hi;
    c1 += wv2[3] * a4.lo; c1 += wv2[4] * a4.hi;
    float s1 = c1.x + c1.y;
    float sp = s0; int ip = 2 * p;
    if (s1 > sp) { sp = s1; ip = 2 * p + 1; }   // strict > : earlier index wins ties
    if (sp > best) { best = sp; bidx = ip; }
}

// Geometry: 512 threads = 8 waves. Each block owns 64 items (item = lane).
// Wave w scans table-pair slice w (8-way split of 1244 pairs). Wave 0 computes
// the MLP for all 64 items once; layer-2 weights shared via LDS. This takes
// total waves from 2048 (2/SIMD, 20% occupancy, VALUBusy 55%) to 8192 (8/SIMD).
__global__ __launch_bounds__(512, 8) void actor_kernel(
    const int* __restrict__ wid, const int* __restrict__ pid,
    const float* __restrict__ wemb, const float* __restrict__ pemb,
    const float* __restrict__ W1, const float* __restrict__ b1,
    const float* __restrict__ W2, const float* __restrict__ b2,
    int* __restrict__ out)
{
    __shared__ v2f   sw[64][5];     // per-item layer-2 weights (2.5 KB)
    __shared__ float sb[8][64];     // per-slice partial best
    __shared__ int   si[8][64];     // per-slice partial argmax

    const int tid  = threadIdx.x;
    const int lane = tid & 63;
    const int wave = tid >> 6;
    const int b    = blockIdx.x * 64 + lane;

    const v4f* __restrict__ tbl4 =
        (const v4f*)__builtin_assume_aligned(pemb, 16);

    if (wave == 0) {
        // ---- gather x (per-lane, divergent vector loads) ----
        const int wi = wid[b];
        const int pi = pid[b];
        const float* __restrict__ wr = wemb + wi * EMB;
        const float* __restrict__ pr = pemb + pi * EMB;
        v2f x2[STATE / 2];
        #pragma unroll
        for (int k = 0; k < EMB / 2; ++k) x2[k] = *(const v2f*)(wr + 2 * k);
        #pragma unroll
        for (int k = 0; k < EMB / 2; ++k) x2[EMB / 2 + k] = *(const v2f*)(pr + 2 * k);

        // ---- layer 1 (weights uniform -> scalar loads; packed FMA) ----
        float hb[HIDDEN];
        #pragma unroll 4
        for (int j = 0; j < HIDDEN; ++j) {
            const v2f* w1r = (const v2f*)(W1 + j * STATE);
            v2f a = w1r[0] * x2[0];
            #pragma unroll
            for (int k = 1; k < STATE / 2; ++k) a += w1r[k] * x2[k];
            hb[j] = fmaxf(a.x + a.y + b1[j], 0.0f);
        }
        v2f h2[HIDDEN / 2];
        #pragma unroll
        for (int k = 0; k < HIDDEN / 2; ++k) h2[k] = (v2f){hb[2 * k], hb[2 * k + 1]};

        // ---- layer 2 -> LDS ----
        #pragma unroll
        for (int d = 0; d < EMB; d += 2) {
            const v2f* w2r0 = (const v2f*)(W2 + d * HIDDEN);
            const v2f* w2r1 = (const v2f*)(W2 + (d + 1) * HIDDEN);
            v2f a0 = w2r0[0] * h2[0];
            v2f a1 = w2r1[0] * h2[0];
            #pragma unroll
            for (int k = 1; k < HIDDEN / 2; ++k) { a0 += w2r0[k] * h2[k]; a1 += w2r1[k] * h2[k]; }
            sw[lane][d / 2] = (v2f){a0.x + a0.y + b2[d], a1.x + a1.y + b2[d + 1]};
        }
    }
    __syncthreads();

    v2f wv2[5];
    #pragma unroll
    for (int k = 0; k < 5; ++k) wv2[k] = sw[lane][k];

    float best = -FLT_MAX;
    int   bidx = 0;

    // pairs p in [1,1245): rows (2p,2p+1). 1244 pairs split 8 ways:
    // slices 0-3 get 156 pairs, slices 4-7 get 155. Ascending index order
    // across waves so the final strict-> reduction keeps first-occurrence ties.
    const int extra = (wave < 4) ? wave : 4;
    const int start = 1 + wave * 155 + extra;
    const int end   = start + 155 + ((wave < 4) ? 1 : 0);

    if (wave == 0) {
        // row 1 alone (row 0 excluded from the table): 8B-aligned loads
        v2f c0v = *(const v2f*)(pemb + 10);
        v4f c1v = *(const v4f*)(pemb + 12);
        v4f c2v = *(const v4f*)(pemb + 16);
        v2f a = wv2[0] * c0v;
        a += wv2[1] * c1v.lo; a += wv2[2] * c1v.hi;
        a += wv2[3] * c2v.lo; a += wv2[4] * c2v.hi;
        best = a.x + a.y; bidx = 1;
    }

    #pragma unroll 4
    for (int p = start; p < end; ++p) score_pair(tbl4, p, wv2, best, bidx);

    // ---- combine 8 slices (ascending slice index -> strict > keeps first-max) ----
    sb[wave][lane] = best;
    si[wave][lane] = bidx;
    __syncthreads();

    if (wave == 0) {
        #pragma unroll
        for (int w = 1; w < 8; ++w) {
            float v  = sb[w][lane];
            int   vi = si[w][lane];
            if (v > best) { best = v; bidx = vi; }
        }
        out[b] = bidx;
    }
}

extern "C" void kernel_launch(void* const* d_in, const int* in_sizes, int n_in,
                              void* d_out, int out_size, void* d_ws, size_t ws_size,
                              hipStream_t stream) {
    const int*   wid  = (const int*)  d_in[0];
    const int*   pid  = (const int*)  d_in[1];
    const float* wemb = (const float*)d_in[2];
    const float* pemb = (const float*)d_in[3];
    const float* W1   = (const float*)d_in[4];
    const float* b1   = (const float*)d_in[5];
    const float* W2   = (const float*)d_in[6];
    const float* b2   = (const float*)d_in[7];
    int* out = (int*)d_out;

    const int B = in_sizes[0];               // 65536
    actor_kernel<<<B / 64, 512, 0, stream>>>(wid, pid, wemb, pemb, W1, b1, W2, b2, out);
}

// Round 2
// 134.362 us; speedup vs baseline: 1.8993x; 1.8993x over previous
//
#include <hip/hip_runtime.h>
#include <float.h>

using v2f = __attribute__((ext_vector_type(2))) float;
using v4f = __attribute__((ext_vector_type(4))) float;

#define EMB 10
#define STATE 20
#define HIDDEN 40
#define NPROJ 2490

// Score one even-aligned row pair (rows 2p, 2p+1). tbl4 is indexed ONLY by a
// compile-time-bounded loop variable p -> provably wave-uniform address ->
// compiler emits pipelined s_load_dwordx4/x16; row data lives in SGPRs and
// feeds v_pk_fma_f32 as the one scalar operand.
__device__ __forceinline__ void score_pair(const v4f* __restrict__ tbl4, int p,
                                           const v2f wv2[5],
                                           float& best, int& bidx) {
    const v4f* tp = tbl4 + p * 5;          // pair base: byte 80*p, 16B-aligned
    v4f a0 = tp[0], a1 = tp[1], a2 = tp[2], a3 = tp[3], a4 = tp[4];
    v2f c0 = wv2[0] * a0.lo;
    c0 += wv2[1] * a0.hi; c0 += wv2[2] * a1.lo;
    c0 += wv2[3] * a1.hi; c0 += wv2[4] * a2.lo;
    float s0 = c0.x + c0.y;
    v2f c1 = wv2[0] * a2.hi;
    c1 += wv2[1] * a3.lo; c1 += wv2[2] * a3.hi;
    c1 += wv2[3] * a4.lo; c1 += wv2[4] * a4.hi;
    float s1 = c1.x + c1.y;
    float sp = s0; int ip = 2 * p;
    if (s1 > sp) { sp = s1; ip = 2 * p + 1; }   // strict > : earlier index wins ties
    if (sp > best) { best = sp; bidx = ip; }
}

// Constant bounds -> p provably uniform -> s_load path guaranteed.
template <int P0, int P1>
__device__ __forceinline__ void scan_range(const v4f* __restrict__ tbl4,
                                           const v2f wv2[5],
                                           float& best, int& bidx) {
    #pragma unroll 4
    for (int p = P0; p < P1; ++p) score_pair(tbl4, p, wv2, best, bidx);
}

// Geometry: 512 threads = 8 waves. Each block owns 64 items (item = lane).
// Wave w scans table-pair slice w (8-way split of 1244 pairs, CONSTANT bounds).
// Wave 0 computes the MLP for all 64 items once; layer-2 weights shared via LDS.
__global__ __launch_bounds__(512, 8) void actor_kernel(
    const int* __restrict__ wid, const int* __restrict__ pid,
    const float* __restrict__ wemb, const float* __restrict__ pemb,
    const float* __restrict__ W1, const float* __restrict__ b1,
    const float* __restrict__ W2, const float* __restrict__ b2,
    int* __restrict__ out)
{
    __shared__ v2f   sw[64][5];     // per-item layer-2 weights (2.5 KB)
    __shared__ float sb[8][64];     // per-slice partial best
    __shared__ int   si[8][64];     // per-slice partial argmax

    const int tid  = threadIdx.x;
    const int lane = tid & 63;
    const int wave = tid >> 6;
    const int b    = blockIdx.x * 64 + lane;

    const v4f* __restrict__ tbl4 =
        (const v4f*)__builtin_assume_aligned(pemb, 16);

    if (wave == 0) {
        // ---- gather x (per-lane, divergent vector loads) ----
        const int wi = wid[b];
        const int pi = pid[b];
        const float* __restrict__ wr = wemb + wi * EMB;
        const float* __restrict__ pr = pemb + pi * EMB;
        v2f x2[STATE / 2];
        #pragma unroll
        for (int k = 0; k < EMB / 2; ++k) x2[k] = *(const v2f*)(wr + 2 * k);
        #pragma unroll
        for (int k = 0; k < EMB / 2; ++k) x2[EMB / 2 + k] = *(const v2f*)(pr + 2 * k);

        // ---- layer 1 (weights uniform -> scalar loads; packed FMA) ----
        float hb[HIDDEN];
        #pragma unroll 4
        for (int j = 0; j < HIDDEN; ++j) {
            const v2f* w1r = (const v2f*)(W1 + j * STATE);
            v2f a = w1r[0] * x2[0];
            #pragma unroll
            for (int k = 1; k < STATE / 2; ++k) a += w1r[k] * x2[k];
            hb[j] = fmaxf(a.x + a.y + b1[j], 0.0f);
        }
        v2f h2[HIDDEN / 2];
        #pragma unroll
        for (int k = 0; k < HIDDEN / 2; ++k) h2[k] = (v2f){hb[2 * k], hb[2 * k + 1]};

        // ---- layer 2 -> LDS ----
        #pragma unroll
        for (int d = 0; d < EMB; d += 2) {
            const v2f* w2r0 = (const v2f*)(W2 + d * HIDDEN);
            const v2f* w2r1 = (const v2f*)(W2 + (d + 1) * HIDDEN);
            v2f a0 = w2r0[0] * h2[0];
            v2f a1 = w2r1[0] * h2[0];
            #pragma unroll
            for (int k = 1; k < HIDDEN / 2; ++k) { a0 += w2r0[k] * h2[k]; a1 += w2r1[k] * h2[k]; }
            sw[lane][d / 2] = (v2f){a0.x + a0.y + b2[d], a1.x + a1.y + b2[d + 1]};
        }
    }
    __syncthreads();

    v2f wv2[5];
    #pragma unroll
    for (int k = 0; k < 5; ++k) wv2[k] = sw[lane][k];

    float best = -FLT_MAX;
    int   bidx = 0;

    if (wave == 0) {
        // row 1 alone (row 0 excluded from the table): 8B-aligned loads
        v2f c0v = *(const v2f*)(pemb + 10);
        v4f c1v = *(const v4f*)(pemb + 12);
        v4f c2v = *(const v4f*)(pemb + 16);
        v2f a = wv2[0] * c0v;
        a += wv2[1] * c1v.lo; a += wv2[2] * c1v.hi;
        a += wv2[3] * c2v.lo; a += wv2[4] * c2v.hi;
        best = a.x + a.y; bidx = 1;
    }

    // pairs p in [1,1245): rows (2p,2p+1). 1244 pairs, 8 constant-bound slices
    // in ascending index order (slices 0-3: 156 pairs, 4-7: 155 pairs).
    switch (wave) {
        case 0: scan_range<   1,  157>(tbl4, wv2, best, bidx); break;
        case 1: scan_range< 157,  313>(tbl4, wv2, best, bidx); break;
        case 2: scan_range< 313,  469>(tbl4, wv2, best, bidx); break;
        case 3: scan_range< 469,  625>(tbl4, wv2, best, bidx); break;
        case 4: scan_range< 625,  780>(tbl4, wv2, best, bidx); break;
        case 5: scan_range< 780,  935>(tbl4, wv2, best, bidx); break;
        case 6: scan_range< 935, 1090>(tbl4, wv2, best, bidx); break;
        case 7: scan_range<1090, 1245>(tbl4, wv2, best, bidx); break;
    }

    // ---- combine 8 slices (ascending slice index -> strict > keeps first-max) ----
    sb[wave][lane] = best;
    si[wave][lane] = bidx;
    __syncthreads();

    if (wave == 0) {
        #pragma unroll
        for (int w = 1; w < 8; ++w) {
            float v  = sb[w][lane];
            int   vi = si[w][lane];
            if (v > best) { best = v; bidx = vi; }
        }
        out[b] = bidx;
    }
}

extern "C" void kernel_launch(void* const* d_in, const int* in_sizes, int n_in,
                              void* d_out, int out_size, void* d_ws, size_t ws_size,
                              hipStream_t stream) {
    const int*   wid  = (const int*)  d_in[0];
    const int*   pid  = (const int*)  d_in[1];
    const float* wemb = (const float*)d_in[2];
    const float* pemb = (const float*)d_in[3];
    const float* W1   = (const float*)d_in[4];
    const float* b1   = (const float*)d_in[5];
    const float* W2   = (const float*)d_in[6];
    const float* b2   = (const float*)d_in[7];
    int* out = (int*)d_out;

    const int B = in_sizes[0];               // 65536
    actor_kernel<<<B / 64, 512, 0, stream>>>(wid, pid, wemb, pemb, W1, b1, W2, b2, out);
}

// Round 3
// 126.279 us; speedup vs baseline: 2.0208x; 1.0640x over previous
//
#include <hip/hip_runtime.h>
#include <float.h>

using v2f = __attribute__((ext_vector_type(2))) float;
using v4f = __attribute__((ext_vector_type(4))) float;

#define EMB 10
#define STATE 20
#define HIDDEN 40
#define NPROJ 2490
#define WAVES 16
#define ITEMS 256           // items per block = 64 lanes x IPL(4)

// Score one even-aligned row pair (rows 2p, 2p+1) for FOUR items per lane.
// tp is wave-uniform (derived from readfirstlane'd bounds) -> s_load path;
// the 80B pair read is amortized over 256 scores instead of 64.
__device__ __forceinline__ void score_pair4(const v4f* __restrict__ tp, int p,
                                            const v2f wv[4][5],
                                            float best[4], int bidx[4]) {
    v4f a0 = tp[0], a1 = tp[1], a2 = tp[2], a3 = tp[3], a4 = tp[4];
    #pragma unroll
    for (int g = 0; g < 4; ++g) {
        v2f c0 = wv[g][0] * a0.lo;
        c0 += wv[g][1] * a0.hi; c0 += wv[g][2] * a1.lo;
        c0 += wv[g][3] * a1.hi; c0 += wv[g][4] * a2.lo;
        float s0 = c0.x + c0.y;
        v2f c1 = wv[g][0] * a2.hi;
        c1 += wv[g][1] * a3.lo; c1 += wv[g][2] * a3.hi;
        c1 += wv[g][3] * a4.lo; c1 += wv[g][4] * a4.hi;
        float s1 = c1.x + c1.y;
        float sp = s0; int ip = 2 * p;
        if (s1 > sp) { sp = s1; ip = 2 * p + 1; }   // strict > : earlier index wins
        if (sp > best[g]) { best[g] = sp; bidx[g] = ip; }
    }
}

// Geometry: 1024 threads = 16 waves, 256 items per block (lane l owns items
// g*64+l, g=0..3). Waves 0-3 compute the MLP (64 items each) -> LDS. All 16
// waves then scan disjoint table slices (uniform bounds via readfirstlane ->
// scalar loads) scoring 4 items per lane. Scalar table traffic per item drops
// 4x vs the previous kernel (the measured per-CU scalar-miss throughput wall).
__global__ __launch_bounds__(1024, 4) void actor_kernel(
    const int* __restrict__ wid, const int* __restrict__ pid,
    const float* __restrict__ wemb, const float* __restrict__ pemb,
    const float* __restrict__ W1, const float* __restrict__ b1,
    const float* __restrict__ W2, const float* __restrict__ b2,
    int* __restrict__ out)
{
    __shared__ v2f   sw[ITEMS][5];      // per-item layer-2 weights (10 KB)
    __shared__ float sb[WAVES][ITEMS];  // per-slice partial best (16 KB)
    __shared__ int   si[WAVES][ITEMS];  // per-slice partial argmax (16 KB)

    const int tid  = threadIdx.x;
    const int lane = tid & 63;
    const int wave = tid >> 6;
    const int itemBase = blockIdx.x * ITEMS;

    const v4f* __restrict__ tbl4 =
        (const v4f*)__builtin_assume_aligned(pemb, 16);

    if (wave < 4) {
        const int b = itemBase + wave * 64 + lane;
        // ---- gather x (per-lane, divergent vector loads) ----
        const int wi = wid[b];
        const int pi = pid[b];
        const float* __restrict__ wr = wemb + wi * EMB;
        const float* __restrict__ pr = pemb + pi * EMB;
        v2f x2[STATE / 2];
        #pragma unroll
        for (int k = 0; k < EMB / 2; ++k) x2[k] = *(const v2f*)(wr + 2 * k);
        #pragma unroll
        for (int k = 0; k < EMB / 2; ++k) x2[EMB / 2 + k] = *(const v2f*)(pr + 2 * k);

        // ---- layer 1 (weights uniform -> scalar loads; packed FMA) ----
        float hb[HIDDEN];
        #pragma unroll 4
        for (int j = 0; j < HIDDEN; ++j) {
            const v2f* w1r = (const v2f*)(W1 + j * STATE);
            v2f a = w1r[0] * x2[0];
            #pragma unroll
            for (int k = 1; k < STATE / 2; ++k) a += w1r[k] * x2[k];
            hb[j] = fmaxf(a.x + a.y + b1[j], 0.0f);
        }
        v2f h2[HIDDEN / 2];
        #pragma unroll
        for (int k = 0; k < HIDDEN / 2; ++k) h2[k] = (v2f){hb[2 * k], hb[2 * k + 1]};

        // ---- layer 2 -> LDS ----
        #pragma unroll
        for (int d = 0; d < EMB; d += 2) {
            const v2f* w2r0 = (const v2f*)(W2 + d * HIDDEN);
            const v2f* w2r1 = (const v2f*)(W2 + (d + 1) * HIDDEN);
            v2f a0 = w2r0[0] * h2[0];
            v2f a1 = w2r1[0] * h2[0];
            #pragma unroll
            for (int k = 1; k < HIDDEN / 2; ++k) { a0 += w2r0[k] * h2[k]; a1 += w2r1[k] * h2[k]; }
            sw[wave * 64 + lane][d / 2] = (v2f){a0.x + a0.y + b2[d], a1.x + a1.y + b2[d + 1]};
        }
    }
    __syncthreads();

    // ---- each lane picks up weights for its 4 items ----
    v2f wv[4][5];
    #pragma unroll
    for (int g = 0; g < 4; ++g) {
        #pragma unroll
        for (int k = 0; k < 5; ++k) wv[g][k] = sw[g * 64 + lane][k];
    }

    float best[4];
    int   bidx[4];
    #pragma unroll
    for (int g = 0; g < 4; ++g) { best[g] = -FLT_MAX; bidx[g] = 1; }

    if (wave == 0) {
        // row 1 alone (row 0 excluded from the table): 8B-aligned loads
        v2f c0v = *(const v2f*)(pemb + 10);
        v4f c1v = *(const v4f*)(pemb + 12);
        v4f c2v = *(const v4f*)(pemb + 16);
        #pragma unroll
        for (int g = 0; g < 4; ++g) {
            v2f a = wv[g][0] * c0v;
            a += wv[g][1] * c1v.lo; a += wv[g][2] * c1v.hi;
            a += wv[g][3] * c2v.lo; a += wv[g][4] * c2v.hi;
            best[g] = a.x + a.y; bidx[g] = 1;
        }
    }

    // pairs p in [1,1245): rows (2p,2p+1). 1244 pairs, 16 slices in ascending
    // order (slices 0-11: 78 pairs, 12-15: 77). Bounds are runtime but forced
    // wave-uniform via readfirstlane -> SGPR loop -> s_load table reads, one
    // shared small loop body (no 16-way code explosion).
    int start = (wave < 12) ? (1 + 78 * wave) : (937 + 77 * (wave - 12));
    int cnt   = (wave < 12) ? 78 : 77;
    start = __builtin_amdgcn_readfirstlane(start);
    cnt   = __builtin_amdgcn_readfirstlane(cnt);

    const v4f* tp = tbl4 + start * 5;
    #pragma unroll 2
    for (int i = 0; i < cnt; ++i, tp += 5)
        score_pair4(tp, start + i, wv, best, bidx);

    // ---- write per-slice partials (ascending slice -> strict > keeps ties) ----
    #pragma unroll
    for (int g = 0; g < 4; ++g) {
        sb[wave][g * 64 + lane] = best[g];
        si[wave][g * 64 + lane] = bidx[g];
    }
    __syncthreads();

    if (tid < ITEMS) {
        float bb = sb[0][tid];
        int   bi = si[0][tid];
        #pragma unroll
        for (int w = 1; w < WAVES; ++w) {
            float v  = sb[w][tid];
            int   vi = si[w][tid];
            if (v > bb) { bb = v; bi = vi; }
        }
        out[itemBase + tid] = bi;
    }
}

extern "C" void kernel_launch(void* const* d_in, const int* in_sizes, int n_in,
                              void* d_out, int out_size, void* d_ws, size_t ws_size,
                              hipStream_t stream) {
    const int*   wid  = (const int*)  d_in[0];
    const int*   pid  = (const int*)  d_in[1];
    const float* wemb = (const float*)d_in[2];
    const float* pemb = (const float*)d_in[3];
    const float* W1   = (const float*)d_in[4];
    const float* b1   = (const float*)d_in[5];
    const float* W2   = (const float*)d_in[6];
    const float* b2   = (const float*)d_in[7];
    int* out = (int*)d_out;

    const int B = in_sizes[0];               // 65536
    actor_kernel<<<B / ITEMS, 1024, 0, stream>>>(wid, pid, wemb, pemb, W1, b1, W2, b2, out);
}